// Round 5
// baseline (803.983 us; speedup 1.0000x reference)
//
#include <hip/hip_runtime.h>
#include <hip/hip_bf16.h>

#define NTOK   65536
#define KCODES 1024
#define DIM    256
#define LOSS_OFF ((size_t)NTOK * DIM)
#define IDX_OFF  (LOSS_OFF + 1)

#define MARGA 3.5e-4f     // a-space margin (d-space 7e-4)

// ---- scratch layout inside the z_q output region (float-slot offsets) ----
// safe: everything is consumed before vq_gather overwrites z_q rows.
#define SC_ZSQ   0              // 65536 f
#define SC_A1    65536          // 65536 f
#define SC_LOSS2 131072         // 65536 f
#define SC_ESQ   196608         // 1024 f
#define SC_PART  197632         // 64 f
#define SC_CNT   197696         // 65536 int
#define SC_LISTS 263232         // 262144 int
#define SC_EH    525376         // 131072 f-slots = 262144 ushort (bf16 emb)

typedef __attribute__((ext_vector_type(8))) short short8;
typedef __attribute__((ext_vector_type(4))) float f32x4;

__device__ __forceinline__ unsigned short f2bf(float x) {
    unsigned u = __float_as_uint(x);
    unsigned r = (u + 0x7FFFu + ((u >> 16) & 1u)) >> 16;   // RNE
    return (unsigned short)r;
}

// numpy pairwise sum-of-squares replica (n=256), as verified in round 4
__device__ __forceinline__ float np_pairwise_sq_128(const float* a) {
    float r[8];
#pragma unroll
    for (int j = 0; j < 8; ++j) {
        float v = a[j]; float sq = v * v;
        asm volatile("" : "+v"(sq));
        r[j] = sq;
    }
    for (int i = 8; i < 128; i += 8) {
#pragma unroll
        for (int j = 0; j < 8; ++j) {
            float v = a[i + j]; float sq = v * v;
            asm volatile("" : "+v"(sq));
            r[j] += sq;
        }
    }
    return ((r[0] + r[1]) + (r[2] + r[3])) + ((r[4] + r[5]) + (r[6] + r[7]));
}
__device__ __forceinline__ float np_rowsq256(const float* row) {
    return np_pairwise_sq_128(row) + np_pairwise_sq_128(row + 128);
}

// faithful fp32 distance: identical arithmetic to the round-4 kernel
__device__ __forceinline__ float faithful_d(const float* __restrict__ z,
                                            const float* __restrict__ emb,
                                            float zsq, float esq, int tok, int c) {
    const float4* zr = (const float4*)(z + (size_t)tok * DIM);
    const float4* er = (const float4*)(emb + (size_t)c * DIM);
    float acc = 0.f;
#pragma unroll 8
    for (int q = 0; q < 64; ++q) {
        float4 a = zr[q], b = er[q];
        acc = fmaf(a.x, b.x, acc); acc = fmaf(a.y, b.y, acc);
        acc = fmaf(a.z, b.z, acc); acc = fmaf(a.w, b.w, acc);
    }
    float t1 = zsq + esq;
    return t1 - 2.0f * acc;
}

// ---------------- kernel: emb prep (faithful esq + bf16 convert) ----------------
__global__ __launch_bounds__(256) void vq_prep_e(const float* __restrict__ emb,
                                                 float* __restrict__ esq,
                                                 unsigned short* __restrict__ eh) {
    int code = blockIdx.x * 256 + threadIdx.x;     // grid 4
    const float* row = emb + (size_t)code * DIM;
    esq[code] = np_rowsq256(row);
    const float4* r4 = (const float4*)row;
#pragma unroll 4
    for (int q = 0; q < 64; ++q) {
        float4 v = r4[q];
        uint2 p;
        p.x = (unsigned)f2bf(v.x) | ((unsigned)f2bf(v.y) << 16);
        p.y = (unsigned)f2bf(v.z) | ((unsigned)f2bf(v.w) << 16);
        *(uint2*)&eh[(size_t)code * DIM + q * 4] = p;
    }
}

// ---------------- kernel: z prep (faithful zsq + cnt reset) ----------------
__global__ __launch_bounds__(256) void vq_prep_z(const float* __restrict__ z,
                                                 float* __restrict__ zsq,
                                                 int* __restrict__ cnt) {
    int tok = blockIdx.x * 256 + threadIdx.x;      // grid 256
    zsq[tok] = np_rowsq256(z + (size_t)tok * DIM);
    cnt[tok] = 0;
}

// ---------------- GEMM filter: PASS 1 = per-token max(a); PASS 2 = enumerate ----------------
template<int PASS>
__global__ __launch_bounds__(256, 2) void vq_gemm(const float* __restrict__ z,
                                                  const unsigned short* __restrict__ eh,
                                                  const float* __restrict__ esq,
                                                  float* __restrict__ a1,
                                                  int* __restrict__ cnt,
                                                  int* __restrict__ lists) {
    __shared__ __align__(16) short zh_s[64 * 256];       // 32 KB, swizzled
    __shared__ __align__(16) short eh_s[2][256 * 32];    // 2 x 16 KB, swizzled
    __shared__ float esqnh_s[1024];                      // 4 KB  (-esq/2)
    __shared__ float a1w_s[4][64];                       // 1 KB (PASS1 merge)

    const int tid = threadIdx.x, bid = blockIdx.x;
    const int w = tid >> 6, l = tid & 63;
    const int t0 = bid * 64;

    // ---- stage zh (convert fp32 z -> bf16, swizzled) ----
#pragma unroll 4
    for (int q = 0; q < 16; ++q) {
        int flat4 = q * 256 + tid;           // 4096 float4s
        int tok = flat4 >> 6;
        int k4  = (flat4 & 63) * 4;
        float4 v = *(const float4*)&z[(size_t)(t0 + tok) * DIM + k4];
        uint2 p;
        p.x = (unsigned)f2bf(v.x) | ((unsigned)f2bf(v.y) << 16);
        p.y = (unsigned)f2bf(v.z) | ((unsigned)f2bf(v.w) << 16);
        int byte = tok * 512 + ((k4 * 2) ^ ((tok & 7) << 4));
        *(uint2*)((char*)zh_s + byte) = p;
    }
    for (int i = tid; i < 1024; i += 256) esqnh_s[i] = -0.5f * esq[i];

    // ---- stage eh slice 0 ----
    uint4 rg[4];
    {
        const int s = 0, c = 0, ks = 0;
        (void)s;
#pragma unroll
        for (int j = 0; j < 4; ++j) {
            int g = tid + 256 * j, lcl = g >> 2, q = g & 3;
            int code = (lcl >> 6) * 256 + c * 64 + (lcl & 63);
            rg[j] = *(const uint4*)&eh[(size_t)code * DIM + ks * 32 + q * 8];
        }
#pragma unroll
        for (int j = 0; j < 4; ++j) {
            int g = tid + 256 * j, lcl = g >> 2, q = g & 3;
            int byte = lcl * 64 + ((q * 16) ^ (((lcl >> 1) & 3) << 4));
            *(uint4*)((char*)&eh_s[0][0] + byte) = rg[j];
        }
    }
    __syncthreads();

    float thrv[4], amax[4];
#pragma unroll
    for (int tf = 0; tf < 4; ++tf) {
        amax[tf] = -3.4e38f;
        if (PASS == 2) thrv[tf] = a1[t0 + tf * 16 + (l & 15)] - MARGA;
    }

    f32x4 acc[4][4];

    for (int c = 0; c < 4; ++c) {
        // init acc with -esq/2 (code-dependent, token-independent)
#pragma unroll
        for (int f = 0; f < 4; ++f) {
            int base = w * 256 + c * 64 + f * 16 + (l >> 4) * 4;
            f32x4 e4 = *(f32x4*)&esqnh_s[base];
#pragma unroll
            for (int tf = 0; tf < 4; ++tf) acc[f][tf] = e4;
        }
        for (int ks = 0; ks < 8; ++ks) {
            int s = c * 8 + ks, buf = s & 1;
            // prefetch next slice into regs
            if (s < 31) {
                int s2 = s + 1, c2 = s2 >> 3, ks2 = s2 & 7;
#pragma unroll
                for (int j = 0; j < 4; ++j) {
                    int g = tid + 256 * j, lcl = g >> 2, q = g & 3;
                    int code = (lcl >> 6) * 256 + c2 * 64 + (lcl & 63);
                    rg[j] = *(const uint4*)&eh[(size_t)code * DIM + ks2 * 32 + q * 8];
                }
            }
            // compute
            short8 bfr[4], afr[4];
#pragma unroll
            for (int tf = 0; tf < 4; ++tf) {
                int tokl = tf * 16 + (l & 15);
                int byte = tokl * 512 + ((ks * 64 + (l >> 4) * 16) ^ ((tokl & 7) << 4));
                bfr[tf] = *(short8*)((char*)zh_s + byte);
            }
#pragma unroll
            for (int f = 0; f < 4; ++f) {
                int lcl = w * 64 + f * 16 + (l & 15);
                int byte = lcl * 64 + (((l >> 4) * 16) ^ (((lcl >> 1) & 3) << 4));
                afr[f] = *(short8*)((char*)&eh_s[buf][0] + byte);
            }
#pragma unroll
            for (int f = 0; f < 4; ++f)
#pragma unroll
                for (int tf = 0; tf < 4; ++tf)
                    acc[f][tf] = __builtin_amdgcn_mfma_f32_16x16x32_bf16(
                        afr[f], bfr[tf], acc[f][tf], 0, 0, 0);

            if (s < 31) {
                __syncthreads();
#pragma unroll
                for (int j = 0; j < 4; ++j) {
                    int g = tid + 256 * j, lcl = g >> 2, q = g & 3;
                    int byte = lcl * 64 + ((q * 16) ^ (((lcl >> 1) & 3) << 4));
                    *(uint4*)((char*)&eh_s[buf ^ 1][0] + byte) = rg[j];
                }
                __syncthreads();
            }
        }
        // fold this 64-code chunk
        if (PASS == 1) {
#pragma unroll
            for (int tf = 0; tf < 4; ++tf) {
                float m0 = fmaxf(fmaxf(acc[0][tf][0], acc[0][tf][1]), fmaxf(acc[0][tf][2], acc[0][tf][3]));
                float m1 = fmaxf(fmaxf(acc[1][tf][0], acc[1][tf][1]), fmaxf(acc[1][tf][2], acc[1][tf][3]));
                float m2 = fmaxf(fmaxf(acc[2][tf][0], acc[2][tf][1]), fmaxf(acc[2][tf][2], acc[2][tf][3]));
                float m3 = fmaxf(fmaxf(acc[3][tf][0], acc[3][tf][1]), fmaxf(acc[3][tf][2], acc[3][tf][3]));
                amax[tf] = fmaxf(amax[tf], fmaxf(fmaxf(m0, m1), fmaxf(m2, m3)));
            }
        } else {
#pragma unroll
            for (int tf = 0; tf < 4; ++tf) {
                int tok = t0 + tf * 16 + (l & 15);
#pragma unroll
                for (int f = 0; f < 4; ++f)
#pragma unroll
                    for (int r = 0; r < 4; ++r) {
                        float a = acc[f][tf][r];
                        if (a >= thrv[tf]) {
                            int code = w * 256 + c * 64 + f * 16 + (l >> 4) * 4 + r;
                            int pos = atomicAdd(&cnt[tok], 1);
                            if (pos < 4) lists[tok * 4 + pos] = code;
                        }
                    }
            }
        }
    }

    if (PASS == 1) {
#pragma unroll
        for (int tf = 0; tf < 4; ++tf) {
            float m = amax[tf];
            m = fmaxf(m, __shfl_xor(m, 16, 64));
            m = fmaxf(m, __shfl_xor(m, 32, 64));
            if (l < 16) a1w_s[w][tf * 16 + l] = m;
        }
        __syncthreads();
        if (tid < 64) {
            float m = fmaxf(fmaxf(a1w_s[0][tid], a1w_s[1][tid]),
                            fmaxf(a1w_s[2][tid], a1w_s[3][tid]));
            a1[t0 + tid] = m;
        }
    }
}

// ---------------- decide: winner per token (idx + loss slot; no z_q write) ----------------
__global__ __launch_bounds__(256) void vq_decide(const float* __restrict__ z,
                                                 const float* __restrict__ emb,
                                                 const float* __restrict__ zsq,
                                                 const float* __restrict__ esq,
                                                 const float* __restrict__ a1,
                                                 const int* __restrict__ cnt,
                                                 const int* __restrict__ lists,
                                                 float* __restrict__ loss2,
                                                 float* __restrict__ dout) {
    const int w = threadIdx.x >> 6, l = threadIdx.x & 63;
    for (int tok = blockIdx.x * 4 + w; tok < NTOK; tok += 512 * 4) {
        int ct = cnt[tok];
        int widx; float dwin;
        if (ct == 1) {
            widx = lists[tok * 4];
            dwin = fmaf(-2.f, a1[tok], zsq[tok]);
        } else if (ct == 2) {
            int cA = lists[tok * 4], cB = lists[tok * 4 + 1];
            if (cB < cA) { int t = cA; cA = cB; cB = t; }
            float dm = 3.4e38f;
            if (l < 2) {
                int c = l ? cB : cA;
                dm = faithful_d(z, emb, zsq[tok], esq[c], tok, c);
            }
            float dA = __shfl(dm, 0, 64), dB = __shfl(dm, 1, 64);
            widx = (dB < dA) ? cB : cA;          // tie -> lower index (cA)
            dwin = fminf(dA, dB);
        } else {  // 0, >=3, or overflow: full faithful scan
            float best = 3.4e38f; int bidx = 0;
            for (int cs = 0; cs < 16; ++cs) {
                int c = cs * 64 + l;
                float d = faithful_d(z, emb, zsq[tok], esq[c], tok, c);
                if (d < best) { best = d; bidx = c; }
            }
#pragma unroll
            for (int m = 1; m < 64; m <<= 1) {
                float od = __shfl_xor(best, m, 64);
                int   oi = __shfl_xor(bidx, m, 64);
                if (od < best || (od == best && oi < bidx)) { best = od; bidx = oi; }
            }
            widx = bidx; dwin = best;
        }
        if (l == 0) {
            dout[IDX_OFF + tok] = (float)widx;
            loss2[tok] = dwin;
        }
    }
}

// ---------------- loss reduction (fixed order) ----------------
__global__ __launch_bounds__(256) void vq_sum(const float* __restrict__ loss2,
                                              float* __restrict__ part) {
    __shared__ float ws[4];
    float s = 0.f;
#pragma unroll
    for (int q = 0; q < 4; ++q)
        s += loss2[blockIdx.x * 1024 + q * 256 + threadIdx.x];
#pragma unroll
    for (int m = 1; m < 64; m <<= 1) s += __shfl_xor(s, m, 64);
    if ((threadIdx.x & 63) == 0) ws[threadIdx.x >> 6] = s;
    __syncthreads();
    if (threadIdx.x == 0) part[blockIdx.x] = ws[0] + ws[1] + ws[2] + ws[3];
}

__global__ __launch_bounds__(64) void vq_final(const float* __restrict__ part,
                                               float* __restrict__ dout) {
    double s = 0.0;
    if (threadIdx.x < 64) s = (double)part[threadIdx.x];
#pragma unroll
    for (int m = 1; m < 64; m <<= 1) s += __shfl_xor(s, m, 64);
    if (threadIdx.x == 0) dout[LOSS_OFF] = (float)(s * 1.25 / 16777216.0);
}

// ---------------- gather z_q rows (after all scratch consumed) ----------------
__global__ __launch_bounds__(256) void vq_gather(const float* __restrict__ emb,
                                                 float* __restrict__ dout) {
    const int w = threadIdx.x >> 6, l = threadIdx.x & 63;
    for (int tok = blockIdx.x * 4 + w; tok < NTOK; tok += 512 * 4) {
        int widx = (int)dout[IDX_OFF + tok];
        float4 ev = *(const float4*)&emb[(size_t)widx * DIM + l * 4];
        *(float4*)&dout[(size_t)tok * DIM + l * 4] = ev;
    }
}

extern "C" void kernel_launch(void* const* d_in, const int* in_sizes, int n_in,
                              void* d_out, int out_size, void* d_ws, size_t ws_size,
                              hipStream_t stream) {
    const float* z   = (const float*)d_in[0];
    const float* emb = (const float*)d_in[1];
    float* out = (float*)d_out;

    float* zsq   = out + SC_ZSQ;
    float* a1    = out + SC_A1;
    float* loss2 = out + SC_LOSS2;
    float* esq   = out + SC_ESQ;
    float* part  = out + SC_PART;
    int*   cnt   = (int*)(out + SC_CNT);
    int*   lists = (int*)(out + SC_LISTS);
    unsigned short* eh = (unsigned short*)(out + SC_EH);

    vq_prep_e<<<4,    256, 0, stream>>>(emb, esq, eh);
    vq_prep_z<<<256,  256, 0, stream>>>(z, zsq, cnt);
    vq_gemm<1><<<1024, 256, 0, stream>>>(z, eh, esq, a1, cnt, lists);
    vq_gemm<2><<<1024, 256, 0, stream>>>(z, eh, esq, a1, cnt, lists);
    vq_decide<<<512,  256, 0, stream>>>(z, emb, zsq, esq, a1, cnt, lists, loss2, out);
    vq_sum   <<<64,   256, 0, stream>>>(loss2, part);
    vq_final <<<1,    64,  0, stream>>>(part, out);
    vq_gather<<<512,  256, 0, stream>>>(emb, out);
}

// Round 6
// 286.474 us; speedup vs baseline: 2.8065x; 2.8065x over previous
//
#include <hip/hip_runtime.h>
#include <hip/hip_bf16.h>

#define NTOK   65536
#define KCODES 1024
#define DIM    256
#define LOSS_OFF ((size_t)NTOK * DIM)
#define IDX_OFF  (LOSS_OFF + 1)

#define MARGA 3.5e-4f     // a-space margin (validated round 5)

// ---- scratch layout inside the z_q output region (float-slot offsets) ----
// all consumed before vq_gather overwrites z_q rows.
#define SC_ZSQ    0              // 65536 f
#define SC_A1     65536          // 65536 f
#define SC_LOSS2  131072         // 65536 f
#define SC_ESQ    196608         // 1024 f
#define SC_ESQNH  197632         // 1024 f  (-esq/2)
#define SC_PART   198656         // 64 f
#define SC_WCNT   198720         // 1 int
#define SC_CNT    198784         // 65536 int
#define SC_LISTS  264320         // 262144 int
#define SC_WLIST  526464         // 65536 int
#define SC_EHIMG  592000         // 131072 f-slots = 512 KB bf16 image (16B aligned)

typedef __attribute__((ext_vector_type(8))) short short8;
typedef __attribute__((ext_vector_type(4))) float f32x4;

__device__ __forceinline__ unsigned f2bf(float x) {
    unsigned u = __float_as_uint(x);
    return (u + 0x7FFFu + ((u >> 16) & 1u)) >> 16;   // RNE
}

__device__ __forceinline__ void gload16(const void* g, void* l) {
    __builtin_amdgcn_global_load_lds((const __attribute__((address_space(1))) unsigned int*)g,
                                     (__attribute__((address_space(3))) unsigned int*)l,
                                     16, 0, 0);
}

// faithful fp32 distance: identical arithmetic to rounds 4/5 (validated)
__device__ __forceinline__ float faithful_d(const float* __restrict__ z,
                                            const float* __restrict__ emb,
                                            float zsq, float esq, int tok, int c) {
    const float4* zr = (const float4*)(z + (size_t)tok * DIM);
    const float4* er = (const float4*)(emb + (size_t)c * DIM);
    float acc = 0.f;
#pragma unroll 8
    for (int q = 0; q < 64; ++q) {
        float4 a = zr[q], b = er[q];
        acc = fmaf(a.x, b.x, acc); acc = fmaf(a.y, b.y, acc);
        acc = fmaf(a.z, b.z, acc); acc = fmaf(a.w, b.w, acc);
    }
    float t1 = zsq + esq;
    return t1 - 2.0f * acc;
}

// wave-parallel numpy pairwise sum-of-squares replica (16 lanes per 256-row).
// lane sub = j + 8*half: r = sum_{i=0..15} fl(a[half*128 + i*8 + j]^2) sequential;
// combine ((r0+r1)+(r2+r3))+((r4+r5)+(r6+r7)) per half, then lo+hi. IEEE add is
// commutative -> shfl_xor tree is bitwise identical to the scalar replica.
__device__ __forceinline__ float np_rowsq256_wave(const float* row, int sub) {
    const int j = sub & 7, half = sub >> 3;
    const float* a = row + half * 128 + j;
    float r = 0.f;
#pragma unroll
    for (int i = 0; i < 16; ++i) {
        float v = a[i * 8];
        float sq = v * v;
        asm volatile("" : "+v"(sq));
        r += sq;
    }
    float t = r + __shfl_xor(r, 1, 64);
    t = t + __shfl_xor(t, 2, 64);
    t = t + __shfl_xor(t, 4, 64);
    t = t + __shfl_xor(t, 8, 64);
    return t;   // correct on sub==0 (and bit-equal on all lanes)
}

// ---------------- prep: esq / esqnh (+ wcnt reset) ----------------
__global__ __launch_bounds__(256) void vq_prep_esq(const float* __restrict__ emb,
                                                   float* __restrict__ esq,
                                                   float* __restrict__ esqnh,
                                                   int* __restrict__ wcnt) {
    if (blockIdx.x == 0 && threadIdx.x == 0) *wcnt = 0;
    int code = blockIdx.x * 16 + (threadIdx.x >> 4);   // grid 64 -> 1024 codes
    int sub = threadIdx.x & 15;
    float tot = np_rowsq256_wave(emb + (size_t)code * DIM, sub);
    if (sub == 0) { esq[code] = tot; esqnh[code] = -0.5f * tot; }
}

// ---------------- prep: zsq + cnt reset ----------------
__global__ __launch_bounds__(256) void vq_prep_z(const float* __restrict__ z,
                                                 float* __restrict__ zsq,
                                                 int* __restrict__ cnt) {
    int tok = blockIdx.x * 16 + (threadIdx.x >> 4);    // grid 4096 -> 65536 rows
    int sub = threadIdx.x & 15;
    float tot = np_rowsq256_wave(z + (size_t)tok * DIM, sub);
    if (sub == 0) { zsq[tok] = tot; cnt[tok] = 0; }
}

// ---------------- prep: bf16 emb image in pre-swizzled LDS slice layout ----------------
// slice (c,ks) 16 KB at (c*8+ks)*16384; within: byte = lcl*64 + ((q*16)^(((lcl>>1)&3)<<4)),
// lcl = (code>>8)*64 + (code&63), holding emb[code][ks*32+q*8 .. +8] as bf16.
__global__ __launch_bounds__(256) void vq_prep_eimg(const float* __restrict__ emb,
                                                    unsigned short* __restrict__ img) {
    int job = blockIdx.x * 256 + threadIdx.x;   // grid 32 -> 8192 (code,ks) jobs
    int code = job >> 3, ks = job & 7;
    int cc = (code >> 6) & 3, lcl = (code >> 8) * 64 + (code & 63);
    const float* src = emb + (size_t)code * DIM + ks * 32;
    char* base = (char*)img + (size_t)(cc * 8 + ks) * 16384;
#pragma unroll
    for (int q = 0; q < 4; ++q) {
        float4 v0 = *(const float4*)&src[q * 8];
        float4 v1 = *(const float4*)&src[q * 8 + 4];
        uint4 p;
        p.x = f2bf(v0.x) | (f2bf(v0.y) << 16);
        p.y = f2bf(v0.z) | (f2bf(v0.w) << 16);
        p.z = f2bf(v1.x) | (f2bf(v1.y) << 16);
        p.w = f2bf(v1.z) | (f2bf(v1.w) << 16);
        *(uint4*)(base + lcl * 64 + ((q * 16) ^ (((lcl >> 1) & 3) << 4))) = p;
    }
}

// ---------------- GEMM filter: PASS1 = per-token max(a); PASS2 = enumerate ----------------
template<int PASS>
__global__ __launch_bounds__(256, 2) void vq_gemm(const float* __restrict__ z,
                                                  const unsigned short* __restrict__ img,
                                                  const float* __restrict__ esqnh,
                                                  float* __restrict__ a1,
                                                  int* __restrict__ cnt,
                                                  int* __restrict__ lists) {
    __shared__ __align__(16) short zh_s[64 * 256];    // 32 KB swizzled
    __shared__ __align__(16) short eh_s[2][8192];     // 2 x 16 KB (async-staged image slices)
    __shared__ float a1w_s[4][64];

    const int tid = threadIdx.x, bid = blockIdx.x;
    const int w = tid >> 6, l = tid & 63;
    const int t0 = bid * 64;

    // stage zh (fp32 -> bf16, swizzled)
#pragma unroll 4
    for (int q = 0; q < 16; ++q) {
        int flat4 = q * 256 + tid;
        int tok = flat4 >> 6;
        int k4  = (flat4 & 63) * 4;
        float4 v = *(const float4*)&z[(size_t)(t0 + tok) * DIM + k4];
        uint2 p;
        p.x = f2bf(v.x) | (f2bf(v.y) << 16);
        p.y = f2bf(v.z) | (f2bf(v.w) << 16);
        int byte = tok * 512 + ((k4 * 2) ^ ((tok & 7) << 4));
        *(uint2*)((char*)zh_s + byte) = p;
    }
    // issue slice 0 (async -> eh_s[0])
    {
        const char* gs = (const char*)img + w * 4096 + l * 16;
        char* ld = (char*)&eh_s[0][0] + w * 4096;
#pragma unroll
        for (int i = 0; i < 4; ++i) gload16(gs + i * 1024, ld + i * 1024);
    }
    __syncthreads();

    float thrv[4], amax[4];
#pragma unroll
    for (int tf = 0; tf < 4; ++tf) {
        amax[tf] = -3.4e38f;
        if (PASS == 2) thrv[tf] = a1[t0 + tf * 16 + (l & 15)] - MARGA;
    }

    f32x4 acc[4][4];

    for (int c = 0; c < 4; ++c) {
#pragma unroll
        for (int f = 0; f < 4; ++f) {
            f32x4 e4 = *(const f32x4*)&esqnh[w * 256 + c * 64 + f * 16 + (l >> 4) * 4];
#pragma unroll
            for (int tf = 0; tf < 4; ++tf) acc[f][tf] = e4;
        }
        for (int ks = 0; ks < 8; ++ks) {
            int s = c * 8 + ks, buf = s & 1;
            if (s < 31) {   // prefetch next slice async into other buffer
                const char* gs = (const char*)img + (size_t)(s + 1) * 16384 + w * 4096 + l * 16;
                char* ld = (char*)&eh_s[buf ^ 1][0] + w * 4096;
#pragma unroll
                for (int i = 0; i < 4; ++i) gload16(gs + i * 1024, ld + i * 1024);
            }
            short8 bfr[4], afr[4];
#pragma unroll
            for (int tf = 0; tf < 4; ++tf) {
                int tokl = tf * 16 + (l & 15);
                int byte = tokl * 512 + ((ks * 64 + (l >> 4) * 16) ^ ((tokl & 7) << 4));
                bfr[tf] = *(short8*)((char*)zh_s + byte);
            }
#pragma unroll
            for (int f = 0; f < 4; ++f) {
                int lcl = w * 64 + f * 16 + (l & 15);
                int byte = lcl * 64 + (((l >> 4) * 16) ^ (((lcl >> 1) & 3) << 4));
                afr[f] = *(short8*)((char*)&eh_s[buf][0] + byte);
            }
#pragma unroll
            for (int f = 0; f < 4; ++f)
#pragma unroll
                for (int tf = 0; tf < 4; ++tf)
                    acc[f][tf] = __builtin_amdgcn_mfma_f32_16x16x32_bf16(
                        afr[f], bfr[tf], acc[f][tf], 0, 0, 0);
            __syncthreads();   // drains prefetch + syncs buffer swap (1 barrier/K-step)
        }
        if (PASS == 1) {
#pragma unroll
            for (int tf = 0; tf < 4; ++tf) {
                float m0 = fmaxf(fmaxf(acc[0][tf][0], acc[0][tf][1]), fmaxf(acc[0][tf][2], acc[0][tf][3]));
                float m1 = fmaxf(fmaxf(acc[1][tf][0], acc[1][tf][1]), fmaxf(acc[1][tf][2], acc[1][tf][3]));
                float m2 = fmaxf(fmaxf(acc[2][tf][0], acc[2][tf][1]), fmaxf(acc[2][tf][2], acc[2][tf][3]));
                float m3 = fmaxf(fmaxf(acc[3][tf][0], acc[3][tf][1]), fmaxf(acc[3][tf][2], acc[3][tf][3]));
                amax[tf] = fmaxf(amax[tf], fmaxf(fmaxf(m0, m1), fmaxf(m2, m3)));
            }
        } else {
#pragma unroll
            for (int tf = 0; tf < 4; ++tf) {
                int tok = t0 + tf * 16 + (l & 15);
#pragma unroll
                for (int f = 0; f < 4; ++f)
#pragma unroll
                    for (int r = 0; r < 4; ++r) {
                        float a = acc[f][tf][r];
                        if (a >= thrv[tf]) {
                            int code = w * 256 + c * 64 + f * 16 + (l >> 4) * 4 + r;
                            int pos = atomicAdd(&cnt[tok], 1);
                            if (pos < 4) lists[tok * 4 + pos] = code;
                        }
                    }
            }
        }
    }

    if (PASS == 1) {
#pragma unroll
        for (int tf = 0; tf < 4; ++tf) {
            float m = amax[tf];
            m = fmaxf(m, __shfl_xor(m, 16, 64));
            m = fmaxf(m, __shfl_xor(m, 32, 64));
            if (l < 16) a1w_s[w][tf * 16 + l] = m;
        }
        __syncthreads();
        if (tid < 64) {
            a1[t0 + tid] = fmaxf(fmaxf(a1w_s[0][tid], a1w_s[1][tid]),
                                 fmaxf(a1w_s[2][tid], a1w_s[3][tid]));
        }
    }
}

// ---------------- decide (fast): thread per token ----------------
__global__ __launch_bounds__(256) void vq_decide_fast(const float* __restrict__ zsq,
                                                      const float* __restrict__ a1,
                                                      const int* __restrict__ cnt,
                                                      const int* __restrict__ lists,
                                                      int* __restrict__ wcnt,
                                                      int* __restrict__ wlist,
                                                      float* __restrict__ loss2,
                                                      float* __restrict__ dout) {
    int t = blockIdx.x * 256 + threadIdx.x;      // grid 256
    int ct = cnt[t];
    if (ct == 1) {
        dout[IDX_OFF + t] = (float)lists[t * 4];
        loss2[t] = fmaf(-2.f, a1[t], zsq[t]);
    } else {
        int pos = atomicAdd(wcnt, 1);
        wlist[pos] = t;
    }
}

// ---------------- decide (hard): wave per ambiguous token ----------------
__global__ __launch_bounds__(256) void vq_decide_hard(const float* __restrict__ z,
                                                      const float* __restrict__ emb,
                                                      const float* __restrict__ zsq,
                                                      const float* __restrict__ esq,
                                                      const int* __restrict__ wcnt,
                                                      const int* __restrict__ wlist,
                                                      const int* __restrict__ cnt,
                                                      const int* __restrict__ lists,
                                                      float* __restrict__ loss2,
                                                      float* __restrict__ dout) {
    const int w = threadIdx.x >> 6, l = threadIdx.x & 63;
    const int n = wcnt[0];
    for (int q = blockIdx.x * 4 + w; q < n; q += 512 * 4) {
        const int tok = wlist[q];
        int ct = cnt[tok];
        int widx; float dwin;
        if (ct <= 4) {
            float d = 3.4e38f; int code = 0x7FFFFFFF;
            if (l < ct) {
                code = lists[tok * 4 + l];
                d = faithful_d(z, emb, zsq[tok], esq[code], tok, code);
            }
#pragma unroll
            for (int m = 1; m < 64; m <<= 1) {
                float od = __shfl_xor(d, m, 64);
                int   oi = __shfl_xor(code, m, 64);
                if (od < d || (od == d && oi < code)) { d = od; code = oi; }
            }
            widx = code; dwin = d;
        } else {   // overflow: full faithful scan
            float best = 3.4e38f; int bidx = 0;
            for (int cs = 0; cs < 16; ++cs) {
                int c = cs * 64 + l;
                float d = faithful_d(z, emb, zsq[tok], esq[c], tok, c);
                if (d < best) { best = d; bidx = c; }
            }
#pragma unroll
            for (int m = 1; m < 64; m <<= 1) {
                float od = __shfl_xor(best, m, 64);
                int   oi = __shfl_xor(bidx, m, 64);
                if (od < best || (od == best && oi < bidx)) { best = od; bidx = oi; }
            }
            widx = bidx; dwin = best;
        }
        if (l == 0) {
            dout[IDX_OFF + tok] = (float)widx;
            loss2[tok] = dwin;
        }
    }
}

// ---------------- loss reduction (fixed order) ----------------
__global__ __launch_bounds__(256) void vq_sum(const float* __restrict__ loss2,
                                              float* __restrict__ part) {
    __shared__ float ws[4];
    float s = 0.f;
#pragma unroll
    for (int q = 0; q < 4; ++q)
        s += loss2[blockIdx.x * 1024 + q * 256 + threadIdx.x];
#pragma unroll
    for (int m = 1; m < 64; m <<= 1) s += __shfl_xor(s, m, 64);
    if ((threadIdx.x & 63) == 0) ws[threadIdx.x >> 6] = s;
    __syncthreads();
    if (threadIdx.x == 0) part[blockIdx.x] = ws[0] + ws[1] + ws[2] + ws[3];
}

__global__ __launch_bounds__(64) void vq_final(const float* __restrict__ part,
                                               float* __restrict__ dout) {
    double s = (double)part[threadIdx.x];
#pragma unroll
    for (int m = 1; m < 64; m <<= 1) s += __shfl_xor(s, m, 64);
    if (threadIdx.x == 0) dout[LOSS_OFF] = (float)(s * 1.25 / 16777216.0);
}

// ---------------- gather z_q rows (after all scratch consumed) ----------------
__global__ __launch_bounds__(256) void vq_gather(const float* __restrict__ emb,
                                                 float* __restrict__ dout) {
    const int w = threadIdx.x >> 6, l = threadIdx.x & 63;
    for (int tok = blockIdx.x * 4 + w; tok < NTOK; tok += 2048 * 4) {
        int widx = (int)dout[IDX_OFF + tok];
        float4 ev = *(const float4*)&emb[(size_t)widx * DIM + l * 4];
        *(float4*)&dout[(size_t)tok * DIM + l * 4] = ev;
    }
}

extern "C" void kernel_launch(void* const* d_in, const int* in_sizes, int n_in,
                              void* d_out, int out_size, void* d_ws, size_t ws_size,
                              hipStream_t stream) {
    const float* z   = (const float*)d_in[0];
    const float* emb = (const float*)d_in[1];
    float* out = (float*)d_out;

    float* zsq   = out + SC_ZSQ;
    float* a1    = out + SC_A1;
    float* loss2 = out + SC_LOSS2;
    float* esq   = out + SC_ESQ;
    float* esqnh = out + SC_ESQNH;
    float* part  = out + SC_PART;
    int*   wcnt  = (int*)(out + SC_WCNT);
    int*   cnt   = (int*)(out + SC_CNT);
    int*   lists = (int*)(out + SC_LISTS);
    int*   wlist = (int*)(out + SC_WLIST);
    unsigned short* img = (unsigned short*)(out + SC_EHIMG);

    vq_prep_esq <<<64,   256, 0, stream>>>(emb, esq, esqnh, wcnt);
    vq_prep_z   <<<4096, 256, 0, stream>>>(z, zsq, cnt);
    vq_prep_eimg<<<32,   256, 0, stream>>>(emb, img);
    vq_gemm<1>  <<<1024, 256, 0, stream>>>(z, img, esqnh, a1, cnt, lists);
    vq_gemm<2>  <<<1024, 256, 0, stream>>>(z, img, esqnh, a1, cnt, lists);
    vq_decide_fast<<<256, 256, 0, stream>>>(zsq, a1, cnt, lists, wcnt, wlist, loss2, out);
    vq_decide_hard<<<512, 256, 0, stream>>>(z, emb, zsq, esq, wcnt, wlist, cnt, lists, loss2, out);
    vq_sum      <<<64,   256, 0, stream>>>(loss2, part);
    vq_final    <<<1,    64,  0, stream>>>(part, out);
    vq_gather   <<<2048, 256, 0, stream>>>(emb, out);
}